// Round 3
// baseline (1004.385 us; speedup 1.0000x reference)
//
#include <hip/hip_runtime.h>
#include <stdint.h>

typedef __attribute__((ext_vector_type(8))) short short8;
typedef __attribute__((ext_vector_type(4))) float f32x4;
typedef __attribute__((ext_vector_type(4))) unsigned short us4;

__device__ __forceinline__ unsigned short f2bf(float f){
  union{float f; unsigned u;} v; v.f = f;
  unsigned r = v.u + 0x7FFFu + ((v.u >> 16) & 1u);
  return (unsigned short)(r >> 16);
}
__device__ __forceinline__ float bflo(unsigned u){
  union{unsigned a; float f;} t; t.a = (u & 0xFFFFu) << 16; return t.f;
}
__device__ __forceinline__ float bfhi(unsigned u){
  union{unsigned a; float f;} t; t.a = u & 0xFFFF0000u; return t.f;
}
__device__ __forceinline__ void dec8(uint4 d, float* r){
  r[0]=bflo(d.x); r[1]=bfhi(d.x); r[2]=bflo(d.y); r[3]=bfhi(d.y);
  r[4]=bflo(d.z); r[5]=bfhi(d.z); r[6]=bflo(d.w); r[7]=bfhi(d.w);
}

// ---------------- pack conv_w -> wA [ks=18][m=128][kk=32] bf16, k=(dh*3+dw)*64+cin
__global__ __launch_bounds__(256) void k_prep(const float* __restrict__ cw,
                                              unsigned short* __restrict__ wA){
  int i = blockIdx.x*256 + threadIdx.x;
  if(i >= 18*128*32) return;
  int kk = i & 31, m = (i >> 5) & 127, ks = i >> 12;
  int k = ks*32 + kk;
  int pos = k >> 6, cin = k & 63;
  int dh = pos/3, dw = pos - dh*3;
  wA[i] = f2bf(cw[((m*64 + cin)*3 + dh)*3 + dw]);
}

// ---------------- x fp32 [b][cin][hw] -> xt bf16 [b][hw][cin] (16B-granule XOR swizzle)
// thread: cin-pair (2 rows) x 8 hw; both loads (float4) and stores (4B words tiling
// full 128-B output rows per wave-instr) are coalesced.
__global__ __launch_bounds__(256) void k_cvt(const float* __restrict__ x,
                                             unsigned* __restrict__ xt32){
  const int b = blockIdx.y;
  const int hw0 = blockIdx.x * 64;
  const int t = threadIdx.x;
  const int cp = t & 31;        // cin pair: cins 2cp, 2cp+1
  const int hq = t >> 5;        // 0..7 -> hw = hw0 + hq*8 + k
  const float* r0 = x + ((size_t)(b*64 + 2*cp))*32768 + hw0 + hq*8;
  const float* r1 = r0 + 32768;
  f32x4 a0 = *(const f32x4*)r0;
  f32x4 a1 = *(const f32x4*)(r0+4);
  f32x4 b0 = *(const f32x4*)r1;
  f32x4 b1 = *(const f32x4*)(r1+4);
  const int g = cp >> 2, wsub = cp & 3;
  unsigned* ob = xt32 + ((size_t)b*32768 + hw0 + (size_t)hq*8)*32;
  #pragma unroll
  for(int k=0;k<8;++k){
    float lo = k<4 ? a0[k] : a1[k-4];
    float hi = k<4 ? b0[k] : b1[k-4];
    unsigned w = ((unsigned)f2bf(lo)) | (((unsigned)f2bf(hi))<<16);
    int hw = hw0 + hq*8 + k;
    ob[(size_t)k*32 + ((g ^ (hw & 7))*4 + wsub)] = w;
  }
}

// ---------------- implicit-GEMM conv + fused BN1 raw stats. craw [b][hw][c] bf16.
__global__ __launch_bounds__(256,2) void k_conv2(
    const unsigned short* __restrict__ xt, const unsigned short* __restrict__ wA,
    unsigned short* __restrict__ craw, float* __restrict__ SsumS, float* __restrict__ SsqS)
{
  const int b = blockIdx.y;
  const int h0 = blockIdx.x * 4;
  __shared__ __align__(16) unsigned short xs[6*64*64];  // 48 KB, swizzled global layout
  __shared__ float redS[128], redQ[128];
  const int t = threadIdx.x;
  const int lane = t & 63, wv = t >> 6;
  {
    const unsigned short* xb = xt + (size_t)b*32768*64;
    for(int i=0;i<12;++i){
      int ch = wv*12 + i;                 // 48 chunks of 1 KB
      int r = ch >> 3, col = ch & 7;
      int hin = h0 - 1 + r;
      hin = hin < 0 ? 1 : (hin > 511 ? 510 : hin);   // reflect pad
      const unsigned short* gsrc = xb + (size_t)hin*4096 + col*512 + lane*8;
      __builtin_amdgcn_global_load_lds(
          (const __attribute__((address_space(1))) unsigned int*)(const void*)gsrc,
          (__attribute__((address_space(3))) unsigned int*)(void*)&xs[ch*512],
          16, 0, 0);
    }
  }
  if(t < 128){ redS[t]=0.f; redQ[t]=0.f; }
  __syncthreads();
  const int r15 = lane & 15, quad = lane >> 4;
  f32x4 acc[8][4];
  #pragma unroll
  for(int mt=0;mt<8;++mt)
    #pragma unroll
    for(int nt=0;nt<4;++nt){ f32x4 z = {0.f,0.f,0.f,0.f}; acc[mt][nt] = z; }
  short8 a_cur[8], a_nxt[8];
  const unsigned short* wb = wA + r15*32 + quad*8;
  #pragma unroll
  for(int mt=0;mt<8;++mt) a_cur[mt] = *(const short8*)(wb + mt*512);
  for(int ks=0; ks<18; ++ks){
    if(ks < 17){
      const unsigned short* wk = wb + (ks+1)*4096;
      #pragma unroll
      for(int mt=0;mt<8;++mt) a_nxt[mt] = *(const short8*)(wk + mt*512);
    }
    const int pos = ks >> 1;
    const int dh = pos < 3 ? 0 : (pos < 6 ? 1 : 2);
    const int dw = pos - dh*3;
    const int g = (ks & 1)*4 + quad;
    const int rr = wv + dh;
    short8 bfr[4];
    #pragma unroll
    for(int nt=0;nt<4;++nt){
      int w = nt*16 + r15;
      int wi = w + dw - 1;
      wi = wi < 0 ? 1 : (wi > 63 ? 62 : wi);         // reflect pad
      bfr[nt] = *(const short8*)&xs[(rr*64 + wi)*64 + ((g ^ (wi & 7))*8)];
    }
    #pragma unroll
    for(int mt=0;mt<8;++mt){
      #pragma unroll
      for(int nt=0;nt<4;++nt)
        acc[mt][nt] = __builtin_amdgcn_mfma_f32_16x16x32_bf16(a_cur[mt], bfr[nt], acc[mt][nt], 0,0,0);
    }
    #pragma unroll
    for(int mt=0;mt<8;++mt) a_cur[mt] = a_nxt[mt];
  }
  // epilogue: D col=lane&15 -> w, row=quad*4+rg -> cout. Pack 4 couts -> 8B store.
  const size_t orow = (size_t)b*32768 + (size_t)(h0 + wv)*64;
  #pragma unroll
  for(int nt=0;nt<4;++nt){
    int w = nt*16 + r15;
    unsigned short* dst = craw + (orow + w)*128 + quad*4;
    #pragma unroll
    for(int mt=0;mt<8;++mt){
      us4 v;
      v[0] = f2bf(acc[mt][nt][0]); v[1] = f2bf(acc[mt][nt][1]);
      v[2] = f2bf(acc[mt][nt][2]); v[3] = f2bf(acc[mt][nt][3]);
      *(us4*)(dst + mt*16) = v;
    }
  }
  // fused BN1 raw stats: sum & sumsq per cout over this block's 4x64 spatial
  #pragma unroll
  for(int mt=0;mt<8;++mt){
    #pragma unroll
    for(int rg=0;rg<4;++rg){
      float s = acc[mt][0][rg]+acc[mt][1][rg]+acc[mt][2][rg]+acc[mt][3][rg];
      float q = acc[mt][0][rg]*acc[mt][0][rg]+acc[mt][1][rg]*acc[mt][1][rg]
              + acc[mt][2][rg]*acc[mt][2][rg]+acc[mt][3][rg]*acc[mt][3][rg];
      #pragma unroll
      for(int m=1;m<16;m<<=1){ s += __shfl_xor(s,m); q += __shfl_xor(q,m); }
      if(r15 == 0){
        int co = mt*16 + quad*4 + rg;
        atomicAdd(&redS[co], s);
        atomicAdd(&redQ[co], q);
      }
    }
  }
  __syncthreads();
  if(t < 128){
    int slot = blockIdx.x & 63;
    atomicAdd(&SsumS[t*64 + slot], redS[t]);
    atomicAdd(&SsqS[t*64 + slot], redQ[t]);
  }
}

__global__ void k_bn1fin(const float* __restrict__ SsumS, const float* __restrict__ SsqS,
                         const float* __restrict__ g1, const float* __restrict__ b1,
                         float* __restrict__ s1, float* __restrict__ t1){
  int c = threadIdx.x; if(c >= 128) return;
  double S = 0.0, Q = 0.0;
  for(int s=0;s<64;++s){ S += (double)SsumS[c*64+s]; Q += (double)SsqS[c*64+s]; }
  const double N = 524288.0;
  double mu = S/N, var = Q/N - mu*mu;
  float sc = (float)((double)g1[c]/sqrt(var + 1e-5));
  s1[c] = sc; t1[c] = (float)((double)b1[c] - mu*(double)sc);
}

// ---------------- h=relu(bn1(craw)); xmT[b][h][c]=mean_w h; Sh/Qh slots; LN slots
// thread = 8 channels x 4 consecutive w; uint4 loads, 1KB/wave-instr coalesced.
__global__ __launch_bounds__(256) void k_passB(
    const unsigned short* __restrict__ craw, const float* __restrict__ s1,
    const float* __restrict__ t1, float* __restrict__ xmT,
    float* __restrict__ ShS, float* __restrict__ QhS,
    float* __restrict__ lnSS, float* __restrict__ lnQS)
{
  const int h = blockIdx.x, b = blockIdx.y;
  const int t = threadIdx.x;
  const int c8 = t & 15, wq = t >> 4;
  const int wv = t >> 6, l = t & 63;
  const int cb = c8*8;
  float A[8], Bv[8];
  #pragma unroll
  for(int j=0;j<8;++j){ A[j] = s1[cb+j]; Bv[j] = t1[cb+j]; }
  const uint4* base = (const uint4*)(craw + ((size_t)b*32768 + (size_t)h*64)*128);
  uint4 d[4];
  #pragma unroll
  for(int k=0;k<4;++k) d[k] = base[(size_t)(wq*4+k)*16 + c8];
  float s8[8] = {0,0,0,0,0,0,0,0}, q8[8] = {0,0,0,0,0,0,0,0};
  #pragma unroll
  for(int k=0;k<4;++k){
    float r[8]; dec8(d[k], r);
    #pragma unroll
    for(int j=0;j<8;++j){
      float v = fmaxf(A[j]*r[j] + Bv[j], 0.f);
      s8[j] += v; q8[j] += v*v;
    }
  }
  #pragma unroll
  for(int j=0;j<8;++j){
    s8[j] += __shfl_xor(s8[j],16); s8[j] += __shfl_xor(s8[j],32);
    q8[j] += __shfl_xor(q8[j],16); q8[j] += __shfl_xor(q8[j],32);
  }
  __shared__ float pS[4][128], pQ[4][128];
  if(l < 16){
    #pragma unroll
    for(int j=0;j<8;++j){ pS[wv][cb+j] = s8[j]; pQ[wv][cb+j] = q8[j]; }
  }
  __syncthreads();
  if(t < 128){
    float S = pS[0][t]+pS[1][t]+pS[2][t]+pS[3][t];
    float Q = pQ[0][t]+pQ[1][t]+pQ[2][t]+pQ[3][t];
    float xmv = S * (1.f/64.f);
    xmT[((size_t)b*512 + h)*128 + t] = xmv;
    atomicAdd(&ShS[t*64 + (h&63)], S);
    atomicAdd(&QhS[t*64 + (h&63)], Q);
    float l1 = xmv, l2 = xmv*xmv;
    #pragma unroll
    for(int m=1;m<64;m<<=1){ l1 += __shfl_xor(l1,m); l2 += __shfl_xor(l2,m); }
    if((t & 63) == 0){
      atomicAdd(&lnSS[b*32 + (h&31)], l1);
      atomicAdd(&lnQS[b*32 + (h&31)], l2);
    }
  }
}

// ---------------- scores f[b,h,k] = xn.xn/sqrt(C), xn normalized inline from xmT
__global__ __launch_bounds__(256) void k_f(const float* __restrict__ xmT,
    const float* __restrict__ lnSS, const float* __restrict__ lnQS, float* __restrict__ f)
{
  const int kt = blockIdx.x, ht = blockIdx.y, b = blockIdx.z;
  __shared__ float Xh[64*129], Xk[64*129];   // [h][c] pitch 129
  __shared__ float musd[2];
  const int t = threadIdx.x;
  if(t == 0){
    float S=0.f, Q=0.f;
    for(int i=0;i<32;++i){ S += lnSS[b*32+i]; Q += lnQS[b*32+i]; }
    float mu = S * (1.f/65536.f);
    float var = Q * (1.f/65536.f) - mu*mu;
    musd[0] = mu; musd[1] = rsqrtf(var + 1e-5f);
  }
  __syncthreads();
  const float mu = musd[0], rs = musd[1];
  const int h0 = ht*64, k0 = kt*64;
  for(int i=0;i<8;++i){
    int idx = t + i*256;             // 2048: row(64) x cq(32)
    int row = idx >> 5, cq = idx & 31;
    f32x4 vh = *(const f32x4*)&xmT[((size_t)b*512 + h0 + row)*128 + cq*4];
    f32x4 vk = *(const f32x4*)&xmT[((size_t)b*512 + k0 + row)*128 + cq*4];
    #pragma unroll
    for(int k=0;k<4;++k){
      Xh[row*129 + cq*4 + k] = (vh[k] - mu)*rs;
      Xk[row*129 + cq*4 + k] = (vk[k] - mu)*rs;
    }
  }
  __syncthreads();
  const int tx = t & 15, ty = t >> 4;
  float acc[4][4] = {{0}};
  for(int c=0;c<128;++c){
    float a[4], bb[4];
    #pragma unroll
    for(int i=0;i<4;++i) a[i] = Xh[(ty*4+i)*129 + c];
    #pragma unroll
    for(int j=0;j<4;++j) bb[j] = Xk[(tx*4+j)*129 + c];
    #pragma unroll
    for(int i=0;i<4;++i)
      #pragma unroll
      for(int j=0;j<4;++j) acc[i][j] += a[i]*bb[j];
  }
  const float s = 0.088388347648318447f;
  #pragma unroll
  for(int i=0;i<4;++i){
    f32x4 o;
    #pragma unroll
    for(int j=0;j<4;++j) o[j] = acc[i][j]*s;
    *(f32x4*)&f[((size_t)b*512 + h0 + ty*4 + i)*512 + k0 + tx*4] = o;
  }
}

// ---------------- softmax over last axis (row of 512 per wave)
__global__ __launch_bounds__(256) void k_sm(float* __restrict__ f)
{
  const int bid = blockIdx.x;
  const int b = bid >> 7, h4 = bid & 127;
  const int t = threadIdx.x, wv = t >> 6, l = t & 63;
  float* row = f + ((size_t)b*512 + h4*4 + wv)*512;
  f32x4 v0 = *(const f32x4*)&row[l*8];
  f32x4 v1 = *(const f32x4*)&row[l*8 + 4];
  float mx = v0[0];
  #pragma unroll
  for(int j=1;j<4;++j) mx = fmaxf(mx, v0[j]);
  #pragma unroll
  for(int j=0;j<4;++j) mx = fmaxf(mx, v1[j]);
  #pragma unroll
  for(int m=1;m<64;m<<=1) mx = fmaxf(mx, __shfl_xor(mx, m));
  float sum = 0.f;
  #pragma unroll
  for(int j=0;j<4;++j){ v0[j] = __expf(v0[j]-mx); sum += v0[j]; }
  #pragma unroll
  for(int j=0;j<4;++j){ v1[j] = __expf(v1[j]-mx); sum += v1[j]; }
  #pragma unroll
  for(int m=1;m<64;m<<=1) sum += __shfl_xor(sum, m);
  float inv = 1.f / sum;
  #pragma unroll
  for(int j=0;j<4;++j){ v0[j] *= inv; v1[j] *= inv; }
  *(f32x4*)&row[l*8] = v0;
  *(f32x4*)&row[l*8+4] = v1;
}

// ---------------- y1[b,m,k] = g_w @ xn + g_b (xn normalized inline)
__global__ __launch_bounds__(256) void k_y1(
    const float* __restrict__ xmT, const float* __restrict__ lnSS, const float* __restrict__ lnQS,
    const float* __restrict__ gw, const float* __restrict__ gb, float* __restrict__ y1)
{
  const int kt = blockIdx.x, b = blockIdx.y;
  __shared__ __align__(16) float GT[128*128];
  __shared__ __align__(16) float XN[128*68];
  __shared__ float musd[2];
  const int t = threadIdx.x;
  if(t == 0){
    float S=0.f, Q=0.f;
    for(int i=0;i<32;++i){ S += lnSS[b*32+i]; Q += lnQS[b*32+i]; }
    float mu = S * (1.f/65536.f);
    float var = Q * (1.f/65536.f) - mu*mu;
    musd[0] = mu; musd[1] = rsqrtf(var + 1e-5f);
  }
  __syncthreads();
  const float mu = musd[0], rs = musd[1];
  const int k0 = kt*64;
  for(int i=0;i<64;++i){
    int idx = t + i*256;
    int o = idx & 127, c = idx >> 7;
    GT[c*128 + o] = gw[o*128 + c];
  }
  for(int i=0;i<32;++i){
    int idx = t + i*256;                // 8192: k(64) x c(128)
    int c = idx & 127, k = idx >> 7;
    XN[c*68 + k] = (xmT[((size_t)b*512 + k0 + k)*128 + c] - mu)*rs;
  }
  __syncthreads();
  const int tx = t & 15, ty = t >> 4;
  float acc[8][4] = {{0}};
  for(int c=0;c<128;++c){
    f32x4 a0 = *(const f32x4*)&GT[c*128 + ty*8];
    f32x4 a1 = *(const f32x4*)&GT[c*128 + ty*8 + 4];
    f32x4 bv = *(const f32x4*)&XN[c*68 + tx*4];
    #pragma unroll
    for(int j=0;j<4;++j){
      #pragma unroll
      for(int i=0;i<4;++i){ acc[i][j] += a0[i]*bv[j]; acc[i+4][j] += a1[i]*bv[j]; }
    }
  }
  #pragma unroll
  for(int i=0;i<8;++i){
    int m = ty*8 + i;
    float bias = gb[m];
    f32x4 o;
    #pragma unroll
    for(int j=0;j<4;++j) o[j] = acc[i][j] + bias;
    *(f32x4*)&y1[((size_t)b*128 + m)*512 + k0 + tx*4] = o;
  }
}

// ---------------- y2t[b,h,m] = sum_k f[b,h,k]*y1[b,m,k]
__global__ __launch_bounds__(256) void k_y2(
    const float* __restrict__ f, const float* __restrict__ y1, float* __restrict__ y2t)
{
  const int ht = blockIdx.x, b = blockIdx.y;
  __shared__ __align__(16) float FT[64*36];
  __shared__ __align__(16) float Y1T[64*132];
  const int t = threadIdx.x;
  const int h0 = ht*32;
  const int tx = t & 15, ty = t >> 4;
  float acc[2][8] = {{0}};
  for(int kc=0;kc<8;++kc){
    int k0 = kc*64;
    __syncthreads();
    for(int i=0;i<8;++i){
      int idx = t + i*256;
      int k = idx & 63, hh = idx >> 6;
      FT[k*36 + hh] = f[((size_t)b*512 + h0 + hh)*512 + k0 + k];
    }
    for(int i=0;i<32;++i){
      int idx = t + i*256;
      int k = idx & 63, m = idx >> 6;
      Y1T[k*132 + m] = y1[((size_t)b*128 + m)*512 + k0 + k];
    }
    __syncthreads();
    for(int kk=0;kk<64;++kk){
      float a0 = FT[kk*36 + ty*2], a1 = FT[kk*36 + ty*2+1];
      f32x4 b0 = *(const f32x4*)&Y1T[kk*132 + tx*8];
      f32x4 b1 = *(const f32x4*)&Y1T[kk*132 + tx*8 + 4];
      #pragma unroll
      for(int j=0;j<4;++j){
        acc[0][j]   += a0*b0[j]; acc[1][j]   += a1*b0[j];
        acc[0][j+4] += a0*b1[j]; acc[1][j+4] += a1*b1[j];
      }
    }
  }
  #pragma unroll
  for(int i=0;i<2;++i){
    int h = h0 + ty*2 + i;
    f32x4 o0, o1;
    #pragma unroll
    for(int j=0;j<4;++j){ o0[j]=acc[i][j]; o1[j]=acc[i][j+4]; }
    float* dst = y2t + ((size_t)b*512 + h)*128 + tx*8;
    *(f32x4*)dst = o0;
    *(f32x4*)(dst+4) = o1;
  }
}

// ---------------- y3T[b,h,o] = out_w @ y2 + out_b, fused BN2-residual stats
__global__ __launch_bounds__(256) void k_y3(
    const float* __restrict__ y2t, const float* __restrict__ ow, const float* __restrict__ obv,
    const float* __restrict__ xmT, float* __restrict__ y3T,
    float* __restrict__ Sy, float* __restrict__ Syy, float* __restrict__ Sxy)
{
  const int ht = blockIdx.x, b = blockIdx.y;
  __shared__ __align__(16) float WT[128*128];
  __shared__ __align__(16) float Y2[128*36];
  __shared__ float ot[32*130];
  const int t = threadIdx.x;
  const int h0 = ht*32;
  for(int i=0;i<64;++i){
    int idx = t + i*256;
    int o = idx & 127, m = idx >> 7;
    WT[m*128 + o] = ow[o*128 + m];
  }
  for(int i=0;i<16;++i){
    int idx = t + i*256;
    int m = idx & 127, hh = idx >> 7;
    Y2[m*36 + hh] = y2t[((size_t)b*512 + h0 + hh)*128 + m];
  }
  __syncthreads();
  const int tx = t & 15, ty = t >> 4;
  float acc[8][2] = {{0}};
  for(int m=0;m<128;++m){
    f32x4 a0 = *(const f32x4*)&WT[m*128 + ty*8];
    f32x4 a1 = *(const f32x4*)&WT[m*128 + ty*8 + 4];
    float b0 = Y2[m*36 + tx*2], b1v = Y2[m*36 + tx*2 + 1];
    #pragma unroll
    for(int i=0;i<4;++i){
      acc[i][0]   += a0[i]*b0; acc[i][1]   += a0[i]*b1v;
      acc[i+4][0] += a1[i]*b0; acc[i+4][1] += a1[i]*b1v;
    }
  }
  float sy[8], syy[8], sxy[8];
  #pragma unroll
  for(int i=0;i<8;++i){
    int o = ty*8 + i;
    float bias = obv[o];
    sy[i]=0.f; syy[i]=0.f; sxy[i]=0.f;
    #pragma unroll
    for(int j=0;j<2;++j){
      int hh = tx*2 + j;
      float v = acc[i][j] + bias;
      ot[hh*130 + o] = v;
      float xmv = xmT[((size_t)b*512 + h0 + hh)*128 + o];
      sy[i] += v; syy[i] += v*v; sxy[i] += v*xmv;
    }
  }
  #pragma unroll
  for(int i=0;i<8;++i){
    #pragma unroll
    for(int m=1;m<16;m<<=1){
      sy[i] += __shfl_xor(sy[i], m); syy[i] += __shfl_xor(syy[i], m); sxy[i] += __shfl_xor(sxy[i], m);
    }
  }
  if(tx == 0){
    #pragma unroll
    for(int i=0;i<8;++i){
      int o = ty*8 + i;
      atomicAdd(&Sy[o], sy[i]); atomicAdd(&Syy[o], syy[i]); atomicAdd(&Sxy[o], sxy[i]);
    }
  }
  __syncthreads();
  for(int i=0;i<4;++i){
    int flat = t + i*256;               // 1024 float4: hh(32) x oq(32)
    int hh = flat >> 5, oq = flat & 31;
    f32x4 v;
    #pragma unroll
    for(int k=0;k<4;++k) v[k] = ot[hh*130 + oq*4 + k];
    *(f32x4*)&y3T[((size_t)b*512 + h0 + hh)*128 + oq*4] = v;
  }
}

__global__ void k_bn2fin(const float* __restrict__ ShS, const float* __restrict__ QhS,
    const float* __restrict__ Sy, const float* __restrict__ Syy, const float* __restrict__ Sxy,
    const float* __restrict__ g2, const float* __restrict__ b2,
    float* __restrict__ s2, float* __restrict__ t2)
{
  int c = threadIdx.x; if(c >= 128) return;
  double Sh = 0.0, Qh = 0.0;
  for(int s=0;s<64;++s){ Sh += (double)ShS[c*64+s]; Qh += (double)QhS[c*64+s]; }
  const double N = 524288.0;
  double S2 = Sh + 64.0*(double)Sy[c];
  double Q2 = Qh + 128.0*(double)Sxy[c] + 64.0*(double)Syy[c];
  double mu = S2/N, var = Q2/N - mu*mu;
  float sc = (float)((double)g2[c]/sqrt(var + 1e-5));
  s2[c] = sc; t2[c] = (float)((double)b2[c] - mu*(double)sc);
}

// ---------------- out = silu(bn2(relu(bn1(craw)) + y3)); no LDS; uint4 in, f32x4 out
__global__ __launch_bounds__(256) void k_final(
    const unsigned short* __restrict__ craw, const float* __restrict__ s1, const float* __restrict__ t1,
    const float* __restrict__ y3T, const float* __restrict__ s2, const float* __restrict__ t2,
    float* __restrict__ out)
{
  const int h = blockIdx.x, b = blockIdx.y;
  const int t = threadIdx.x;
  const int c8 = t & 15, wq = t >> 4;   // 8 channels, 4 consecutive w
  const int cb = c8*8;
  float A[8], Bv[8], C[8], D[8], Y[8];
  #pragma unroll
  for(int j=0;j<8;++j){
    A[j]=s1[cb+j]; Bv[j]=t1[cb+j]; C[j]=s2[cb+j]; D[j]=t2[cb+j];
    Y[j]=y3T[((size_t)b*512 + h)*128 + cb + j];
  }
  const uint4* base = (const uint4*)(craw + ((size_t)b*32768 + (size_t)h*64)*128);
  uint4 d[4];
  #pragma unroll
  for(int k=0;k<4;++k) d[k] = base[(size_t)(wq*4+k)*16 + c8];
  float vals[8][4];
  #pragma unroll
  for(int k=0;k<4;++k){
    float r[8]; dec8(d[k], r);
    #pragma unroll
    for(int j=0;j<8;++j){
      float hv = fmaxf(A[j]*r[j] + Bv[j], 0.f) + Y[j];
      float z = C[j]*hv + D[j];
      vals[j][k] = z / (1.f + __expf(-z));
    }
  }
  float* ob = out + ((size_t)b*128 + cb)*32768 + (size_t)h*64 + wq*4;
  #pragma unroll
  for(int j=0;j<8;++j){
    f32x4 o; o[0]=vals[j][0]; o[1]=vals[j][1]; o[2]=vals[j][2]; o[3]=vals[j][3];
    *(f32x4*)(ob + (size_t)j*32768) = o;
  }
}

extern "C" void kernel_launch(void* const* d_in, const int* in_sizes, int n_in,
                              void* d_out, int out_size, void* d_ws, size_t ws_size,
                              hipStream_t stream)
{
  const float* x      = (const float*)d_in[0];
  const float* conv_w = (const float*)d_in[1];
  const float* bn1_g  = (const float*)d_in[2];
  const float* bn1_b  = (const float*)d_in[3];
  const float* g_w    = (const float*)d_in[4];
  const float* g_b    = (const float*)d_in[5];
  const float* out_w  = (const float*)d_in[6];
  const float* out_b  = (const float*)d_in[7];
  const float* bn2_g  = (const float*)d_in[8];
  const float* bn2_b  = (const float*)d_in[9];
  float* out = (float*)d_out;
  char* ws = (char*)d_ws;

  // ---- ws layout (zeroed region first; high-water ~138.6 MB) ----
  float* SsumS = (float*)(ws + 0);        // 128*64
  float* SsqS  = (float*)(ws + 32768);    // 128*64
  float* ShS   = (float*)(ws + 65536);    // 128*64
  float* QhS   = (float*)(ws + 98304);    // 128*64
  float* lnSS  = (float*)(ws + 131072);   // 16*32
  float* lnQS  = (float*)(ws + 133120);   // 16*32
  float* Sy    = (float*)(ws + 135168);   // 128
  float* Syy   = (float*)(ws + 135680);   // 128
  float* Sxy   = (float*)(ws + 136192);   // 128  -> zero region ends 136704
  float* s1    = (float*)(ws + 136704);
  float* t1    = (float*)(ws + 137216);
  float* s2    = (float*)(ws + 137728);
  float* t2    = (float*)(ws + 138240);
  float* y3T   = (float*)(ws + 138752);                    // 4 MB
  unsigned short* craw = (unsigned short*)(ws + 4333568);  // 134.2 MB

  // ---- dead-before-k_final intermediates live in d_out (268 MB) ----
  char* ob = (char*)d_out;
  unsigned short* xt  = (unsigned short*)(ob + 0);          // 67.1 MB
  float* xmT = (float*)(ob + 67108864);                     // 4 MB
  float* f   = (float*)(ob + 71303168);                     // 16 MB
  float* y1  = (float*)(ob + 88080384);                     // 4 MB
  float* y2t = (float*)(ob + 92274688);                     // 4 MB
  unsigned short* wA = (unsigned short*)(ob + 96468992);    // 147 KB

  hipMemsetAsync(ws, 0, 136704, stream);
  hipLaunchKernelGGL(k_prep,   dim3(288),      dim3(256), 0, stream, conv_w, wA);
  hipLaunchKernelGGL(k_cvt,    dim3(512,16),   dim3(256), 0, stream, x, (unsigned*)xt);
  hipLaunchKernelGGL(k_conv2,  dim3(128,16),   dim3(256), 0, stream, xt, wA, craw, SsumS, SsqS);
  hipLaunchKernelGGL(k_bn1fin, dim3(1),        dim3(128), 0, stream, SsumS, SsqS, bn1_g, bn1_b, s1, t1);
  hipLaunchKernelGGL(k_passB,  dim3(512,16),   dim3(256), 0, stream, craw, s1, t1, xmT, ShS, QhS, lnSS, lnQS);
  hipLaunchKernelGGL(k_f,      dim3(8,8,16),   dim3(256), 0, stream, xmT, lnSS, lnQS, f);
  hipLaunchKernelGGL(k_sm,     dim3(2048),     dim3(256), 0, stream, f);
  hipLaunchKernelGGL(k_y1,     dim3(8,16),     dim3(256), 0, stream, xmT, lnSS, lnQS, g_w, g_b, y1);
  hipLaunchKernelGGL(k_y2,     dim3(16,16),    dim3(256), 0, stream, f, y1, y2t);
  hipLaunchKernelGGL(k_y3,     dim3(16,16),    dim3(256), 0, stream, y2t, out_w, out_b, xmT, y3T, Sy, Syy, Sxy);
  hipLaunchKernelGGL(k_bn2fin, dim3(1),        dim3(128), 0, stream, ShS, QhS, Sy, Syy, Sxy, bn2_g, bn2_b, s2, t2);
  hipLaunchKernelGGL(k_final,  dim3(512,16),   dim3(256), 0, stream, craw, s1, t1, y3T, s2, t2, out);
}